// Round 17
// baseline (181.894 us; speedup 1.0000x reference)
//
#include <hip/hip_runtime.h>

// ---------------- problem constants ----------------
#define B_     8192
#define D_     32
#define H_     128
#define PH_    64
#define PREP_  10
#define CS_    8
#define CH_    32
#define NT_    16
#define NO_    4096
#define NPOST_ 4
#define DT_    0.1f
#define TWO_LOGC 1.8378770664093453f   // 2*log(sqrt(2*pi))

// ---------------- bf16 fragment-blob offsets (ushort elements) ----------------
// blob layout for a KxN weight: element ((kc*ntiles+nt)*64+lane)*8+j holds
// W[kc*32 + 4*((lane>>4)&3) + (j&3) + 16*(j>>2)][nt*16 + (lane&15)]
// FXZXN = PW2 @ [xz_w | xn_w] (64x256); WIH = w_ih (320x384), WHH (128x384).
#define OFF_XZXN 0        // FXZXN 64x256 -> 16384
#define OFF_HZ   16384    // 128x128  -> 16384
#define OFF_HN   32768    // 128x128  -> 16384
#define OFF_PW1  49152    // 128x64   -> 8192
#define OFF_PW2  57344    // 64x64    -> 4096
#define OFF_WIH  61440    // 320x384  -> 122880
#define OFF_WHH  184320   // 128x384  -> 49152
#define BLOB_ELEMS 233472
#define INV_BYTE_OFF ((size_t)BLOB_ELEMS*2)
#define WJP_BYTE_OFF (INV_BYTE_OFF + 262144)   // float[32*51 + 256]: prep coeffs + folded euler bias

// LDS-resident weight copies (ushort offsets inside wlds)
#define WL_XZXN 0
#define WL_HZ   16384
#define WL_PW1  32768
#define WL_PW2  40960
#define WL_TOT  45056      // 88 KB

// activation LDS strides (ushorts): stride_dw % 32 == 4 -> worst 2-way (free)
#define STRH 136
#define STRP 72
#define STRG 328

// shared fp32 constant table offsets (floats)
#define SB_XZ    0
#define SB_XN    128
#define SB_P1    256
#define SB_P2    320
#define SB_BRZ   384      // b_ih+b_hh for r (0..127) and z (128..255)
#define SB_BIN   640      // b_ih n-chunk
#define SB_BHN   768      // b_hh n-chunk
#define SB_TOT   896

typedef float f4  __attribute__((ext_vector_type(4)));
typedef short bf8 __attribute__((ext_vector_type(8)));

__device__ __forceinline__ f4 mfma16(bf8 a, bf8 b, f4 c){
  return __builtin_amdgcn_mfma_f32_16x16x32_bf16(a,b,c,0,0,0);
}
__device__ __forceinline__ unsigned short f2bf(float f){
  unsigned int u = __builtin_bit_cast(unsigned int, f);
  u = (u + 0x7FFFu + ((u>>16)&1u)) >> 16;
  return (unsigned short)u;
}
// pack 2 floats -> 2 bf16 (RNE) in one op
__device__ __forceinline__ unsigned int cvtpk(float lo, float hi){
  unsigned int r;
  asm("v_cvt_pk_bf16_f32 %0, %1, %2" : "=v"(r) : "v"(lo), "v"(hi));
  return r;
}
__device__ __forceinline__ float sigmoidf_(float x){ return 1.f/(1.f+__expf(-x)); }
// fast tanh: exact formula, 5 ops, saturates correctly.
__device__ __forceinline__ float tanhf_(float x){
  float e = __expf(2.f*x);
  return 1.f - 2.f/(e+1.f);
}
// column k -> ushort position inside a swizzled activation row (fragment order)
__device__ __forceinline__ int permk(int k){
  return ((k>>5)<<5) | (((k>>2)&3)<<3) | (((k>>4)&1)<<2) | (k&3);
}

// Wave-sliced GEMM: rows = NRT*16, wave owns col tiles {tile0 + s*TSTR : s<NSEL}
// of an NTT-tile-wide fragment blob. A from swizzled LDS (1 ds_read_b128 per
// row-tile per kc), B streamed from L2 blob OR LDS-resident copy (same layout).
// unroll 2 caps the in-flight load window (anti-spill; R2/R3/R9 lesson).
template<int NKC,int NSEL,int NTT,int NRT,int TSTR=8>
__device__ __forceinline__ void gemmW(f4 (&acc)[NRT][NSEL], const unsigned short* Ald,
                                      int strideUsh, const unsigned short* __restrict__ Bg,
                                      int lane, int tile0){
  const int lc = lane & 15, a4 = lane >> 4;
  const unsigned short* a0 = Ald + lc*strideUsh + a4*8;
  const unsigned short* bl = Bg + (size_t)tile0*512 + lane*8;
  #pragma unroll 2
  for(int kc=0;kc<NKC;kc++){
    bf8 av0 = *(const bf8*)(a0 + kc*32);
    bf8 av1;
    if constexpr(NRT==2) av1 = *(const bf8*)(a0 + 16*strideUsh + kc*32);
    #pragma unroll
    for(int s=0;s<NSEL;s++){
      bf8 bv = *(const bf8*)(bl + (size_t)(kc*NTT + s*TSTR)*512);
      acc[0][s] = mfma16(av0, bv, acc[0][s]);
      if constexpr(NRT==2) acc[1][s] = mfma16(av1, bv, acc[1][s]);
    }
  }
}

// ---------------- prep kernels ----------------
__global__ void init_inv(unsigned short* inv, float* outLoss){
  int i = blockIdx.x*256 + threadIdx.x;
  if(i < NT_*B_) inv[i] = 0xFFFFu;
  if(i == 0) *outLoss = 0.f;
}

__global__ void scatter_inv(unsigned short* inv, const int* __restrict__ obs){
  int i = blockIdx.x*256 + threadIdx.x;
  if(i < NT_*NO_){
    int t = i >> 12;
    int o = i & 4095;
    inv[(size_t)t*B_ + obs[i]] = (unsigned short)o;
  }
}

__global__ void build_blobs(const float* __restrict__ pw1, const float* __restrict__ pw2,
                            const float* __restrict__ xzw, const float* __restrict__ xnw,
                            const float* __restrict__ hzw, const float* __restrict__ hnw,
                            const float* __restrict__ wih, const float* __restrict__ whh,
                            const float* __restrict__ wprep, const float* __restrict__ bprep,
                            const float* __restrict__ pb2, const float* __restrict__ xzb,
                            const float* __restrict__ xnb,
                            unsigned short* __restrict__ blob, float* __restrict__ wjp){
  int sec = blockIdx.y;
  int e = blockIdx.x*256 + threadIdx.x;
  if(sec==7){
    // repack w_prep [d][4][10] + bias_prep [d][10] -> wjp [d][pr][5], row stride 51
    if(e < 32*51){
      int d = e/51, r = e%51, pr = r/5, c = r%5;
      float v = 0.f;
      if(pr < PREP_) v = (c<4) ? wprep[d*40 + c*10 + pr] : bprep[d*10 + pr];
      wjp[e] = v;
    } else if(e < 32*51 + 256){
      // folded euler bias: fb[n] = b2 @ XZXN[:,n] + [xz_b|xn_b][n]
      int n = e - 32*51;
      float acc = (n<128)? xzb[n] : xnb[n-128];
      for(int m=0;m<2*D_;m++){
        float xz = (n<128)? xzw[(size_t)m*H_+n] : xnw[(size_t)m*H_+(n-128)];
        acc += pb2[m]*xz;
      }
      wjp[e] = acc;
    }
    return;
  }
  const float* src=nullptr; int N, ld, off, cnt;
  switch(sec){
    case 0: src=nullptr; N=256; ld=0;   off=OFF_XZXN; cnt=16384;  break; // FXZXN = pw2 @ [xz|xn]
    case 1: src=hzw;  N=128; ld=128; off=OFF_HZ;   cnt=16384;  break;
    case 2: src=hnw;  N=128; ld=128; off=OFF_HN;   cnt=16384;  break;
    case 3: src=pw1;  N=64;  ld=64;  off=OFF_PW1;  cnt=8192;   break;
    case 4: src=pw2;  N=64;  ld=64;  off=OFF_PW2;  cnt=4096;   break;
    case 5: src=wih;  N=384; ld=384; off=OFF_WIH;  cnt=122880; break;
    default:src=whh;  N=384; ld=384; off=OFF_WHH;  cnt=49152;  break;
  }
  if(e >= cnt) return;
  int ntiles = N >> 4;
  int perkc = ntiles << 9;
  int kc = e / perkc, rem = e % perkc;
  int nt = rem >> 9, li = rem & 511;
  int lane = li >> 3, j = li & 7;
  int n = nt*16 + (lane & 15);
  int k = kc*32 + ((lane>>4)&3)*4 + (j&3) + ((j>>2)<<4);
  float v;
  if(sec==0){
    // FXZXN[k][n] = sum_m pw2[k][m] * XZXN[m][n], k in [0,64)
    float acc = 0.f;
    #pragma unroll 4
    for(int m=0;m<2*D_;m++){
      float xz = (n<128)? xzw[(size_t)m*H_+n] : xnw[(size_t)m*H_+(n-128)];
      acc += pw2[(size_t)k*(2*D_)+m]*xz;
    }
    v = acc;
  }
  else v = src[(size_t)k*ld + n];
  blob[off + e] = f2bf(v);
}

// ---------------- fused persistent kernel ----------------
// 256 blocks x 512 threads (8 waves = 2 waves/SIMD); 32 rows/block.
// R17 vs R16: mid-loop P-phase DELETED. Each wave redundantly computes the
// 16-row p-tile containing its gin rows (4w..4w+3) from LDS qb/PW2 (8 MFMA),
// stages 4 rows x 64 cols to a wave-private LDS strip (wave-internal DS
// ordering, no barrier), and gin reads from there. Per-t barriers 7 -> 6;
// the p-GEMM now overlaps gh's L2 streaming inside jump phase A.
__global__ __launch_bounds__(512,2) void fused(
    const float* __restrict__ X, const float* __restrict__ M,
    const float* __restrict__ cov,
    const float* __restrict__ cm_w1, const float* __restrict__ cm_b1,
    const float* __restrict__ cm_w2, const float* __restrict__ cm_b2,
    const float* __restrict__ p_b1, const float* __restrict__ p_b2,
    const float* __restrict__ b_ih, const float* __restrict__ b_hh,
    const unsigned short* __restrict__ blob, const float* __restrict__ wjp,
    const unsigned short* __restrict__ inv,
    float* __restrict__ outH, float* __restrict__ outP, float* __restrict__ outLoss)
{
  __shared__ __align__(16) unsigned short wlds[WL_TOT];  // 88KB resident weights
  __shared__ __align__(16) unsigned short hb[32*STRH];   // bf16 h (swizzled)
  __shared__ __align__(16) unsigned short qb[32*STRP];   // bf16 q (swizzled)
  __shared__ __align__(16) unsigned short un[32*STRG];   // union: zh / gin
  __shared__ __align__(16) float wp[8*272];              // wave-private p strips [8][4][68]
  __shared__ float sb[SB_TOT];
  __shared__ float sbJ[32*51];                           // packed prep coeffs
  __shared__ int obsO[32];
  __shared__ float lred[8];

  const int tid  = threadIdx.x;
  const int lane = tid & 63;
  const int w    = tid >> 6;           // wave 0..7
  const int lc   = lane & 15;
  const int a4   = lane >> 4;          // 0..3
  const int base = blockIdx.x * 32;
  float lsum = 0.f;

  // ---- stage fp32 constants + resident weights ----
  const float* fb = wjp + 32*51;
  for(int i=tid;i<128;i+=512){ sb[SB_XZ+i]=fb[i]; sb[SB_XN+i]=fb[128+i];
                               sb[SB_BIN+i]=b_ih[256+i]; sb[SB_BHN+i]=b_hh[256+i]; }
  for(int i=tid;i<64;i+=512){ sb[SB_P1+i]=p_b1[i]; sb[SB_P2+i]=p_b2[i]; }
  for(int i=tid;i<256;i+=512) sb[SB_BRZ+i]=b_ih[i]+b_hh[i];
  for(int i=tid;i<32*51;i+=512) sbJ[i]=wjp[i];
  for(int i=tid*8;i<32768;i+=4096) *(uint4*)(wlds+i)      = *(const uint4*)(blob+i);        // FXZXN|HZ
  for(int i=tid*8;i<12288;i+=4096) *(uint4*)(wlds+32768+i)= *(const uint4*)(blob+49152+i);  // PW1|PW2

  // ---- init h = tanh(relu(cov@cm_w1+b1)@cm_w2+b2) (one-time scalar path) ----
  {
    float* c1f = wp;                    // [32][36] scratch (wp is 2176 floats)
    float* hInitF = (float*)un;         // [32][132] scratch
    int row = tid>>4, q = tid&15;
    float a[2];
    #pragma unroll
    for(int j=0;j<2;j++) a[j]=cm_b1[q*2+j];
    #pragma unroll
    for(int k=0;k<CS_;k++){
      float cv = cov[(size_t)(base+row)*CS_+k];
      #pragma unroll
      for(int j=0;j<2;j++) a[j] += cv*cm_w1[k*CH_+q*2+j];
    }
    #pragma unroll
    for(int j=0;j<2;j++) c1f[row*36+q*2+j] = fmaxf(a[j],0.f);
    __syncthreads();
    float acc2[8];
    #pragma unroll
    for(int j=0;j<8;j++) acc2[j]=cm_b2[q*8+j];
    for(int k=0;k<CH_;k++){
      float cv = c1f[row*36+k];
      #pragma unroll
      for(int j=0;j<8;j++) acc2[j] += cv*cm_w2[k*H_+q*8+j];
    }
    #pragma unroll
    for(int j=0;j<8;j++) hInitF[row*132+q*8+j] = tanhf_(acc2[j]);
    __syncthreads();
  }

  f4 hFr[2];        // h cols [16w,16w+16), rows rt*16+a4*4+g
  f4 pFr;           // final p, rows prt*16+a4*4+g, col pct*16+lc
  const int prt = w & 1, pct = w >> 1;
  {
    float* hInitF = (float*)un;
    #pragma unroll
    for(int rt=0;rt<2;rt++)
      #pragma unroll
      for(int g=0;g<4;g++)
        hFr[rt][g] = hInitF[(rt*16+a4*4+g)*132 + w*16+lc];
    __syncthreads();                    // reads done before un reuse / hb write
    #pragma unroll
    for(int rt=0;rt<2;rt++)
      #pragma unroll
      for(int g=0;g<4;g++)
        hb[(rt*16+a4*4+g)*STRH + permk(w*16+lc)] = f2bf(hFr[rt][g]);
    __syncthreads();
  }

  // ---- Q-phase: q = relu(h@PW1+b1) -> qb; wave w -> rows 16*prt, cols 16*pct ----
  auto qphase = [&](){
    f4 acc[1][1];
    { float bv = sb[SB_P1 + pct*16+lc]; f4 t={bv,bv,bv,bv}; acc[0][0]=t; }
    gemmW<4,1,4,1>(acc, hb + prt*16*STRH, STRH, wlds+WL_PW1, lane, pct);
    #pragma unroll
    for(int g=0;g<4;g++)
      qb[(prt*16+a4*4+g)*STRP + permk(pct*16+lc)] = f2bf(fmaxf(acc[0][0][g],0.f));
    __syncthreads();
  };

  // ---- euler: h += DT*(1-z)*(n-h); q@FXZXN + h@HZ from LDS; HN prefetched ----
  auto euler = [&](){
    // T14 issue-early: HN B-fragments (L2) in flight across phase 1 + barrier
    bf8 hnB[4];
    #pragma unroll
    for(int kc=0;kc<4;kc++)
      hnB[kc] = *(const bf8*)(blob + OFF_HN + (size_t)(kc*8+w)*512 + lane*8);
    f4 ax[2][2];   // [rt][0]=xz part, [rt][1]=xn part (merged 256-wide blob)
    #pragma unroll
    for(int rt=0;rt<2;rt++){
      float bz = sb[SB_XZ + w*16+lc], bn = sb[SB_XN + w*16+lc];
      f4 tz={bz,bz,bz,bz}, tn={bn,bn,bn,bn};
      ax[rt][0]=tz; ax[rt][1]=tn;
    }
    gemmW<2,2,16,2>(ax, qb, STRP, wlds+WL_XZXN, lane, w);
    f4 ah[2][1]; { f4 z4={0.f,0.f,0.f,0.f}; ah[0][0]=z4; ah[1][0]=z4; }
    gemmW<4,1,8,2>(ah, hb, STRH, wlds+WL_HZ, lane, w);
    f4 zr[2];
    #pragma unroll
    for(int rt=0;rt<2;rt++)
      #pragma unroll
      for(int g=0;g<4;g++){
        float z = sigmoidf_(ax[rt][0][g] + ah[rt][0][g]);
        zr[rt][g]=z;
        un[(rt*16+a4*4+g)*STRH + permk(w*16+lc)] = f2bf(z*hFr[rt][g]);   // zh
      }
    __syncthreads();
    // ah2 = zh @ HN with the prefetched B fragments
    f4 ah2[2]; { f4 z4={0.f,0.f,0.f,0.f}; ah2[0]=z4; ah2[1]=z4; }
    {
      const unsigned short* a0 = un + lc*STRH + a4*8;
      #pragma unroll
      for(int kc=0;kc<4;kc++){
        bf8 av0 = *(const bf8*)(a0 + kc*32);
        bf8 av1 = *(const bf8*)(a0 + 16*STRH + kc*32);
        ah2[0] = mfma16(av0, hnB[kc], ah2[0]);
        ah2[1] = mfma16(av1, hnB[kc], ah2[1]);
      }
    }
    #pragma unroll
    for(int rt=0;rt<2;rt++)
      #pragma unroll
      for(int g=0;g<4;g++){
        float nn = tanhf_(ax[rt][1][g] + ah2[rt][g]);
        float ho = hFr[rt][g];
        float hv = ho + DT_*(1.f-zr[rt][g])*(nn-ho);
        hFr[rt][g]=hv;
        hb[(rt*16+a4*4+g)*STRH + permk(w*16+lc)] = f2bf(hv);
      }
    __syncthreads();
  };

  // ---- Bayesian jump (R17):
  //  phase A: preload gi kc0; gh GEMM (hb, L2); REDUNDANT p-tile GEMM (qb,
  //           LDS) -> wave-private wp strip (no barrier: wave-internal DS);
  //           gin VALU (reads wp, writes un)           -> barrier
  //  phase B: gi GEMM (peeled kc0 + stream) + epilogue -> barrier
  auto jump = [&](int o0, int o1, float x0, float m0, float x1, float m1){
    bf8 pre[3];
    #pragma unroll
    for(int s=0;s<3;s++)
      pre[s] = *(const bf8*)(blob + OFF_WIH + (size_t)(w + s*8)*512 + lane*8);
    // gh = h @ [whh_r|whh_z|whh_n] (+ b_hh n-chunk)
    f4 gh[2][3];
    #pragma unroll
    for(int rt=0;rt<2;rt++){
      float bhn = sb[SB_BHN + w*16+lc];
      f4 z4={0.f,0.f,0.f,0.f}, tn={bhn,bhn,bhn,bhn};
      gh[rt][0]=z4; gh[rt][1]=z4; gh[rt][2]=tn;
    }
    gemmW<4,3,24,2>(gh, hb, STRH, blob+OFF_WHH, lane, w);
    // redundant p: 16-row tile (w>>2) x all 64 cols, from LDS qb/PW2
    {
      f4 pa[1][4];
      #pragma unroll
      for(int s=0;s<4;s++){ float bv = sb[SB_P2 + s*16+lc]; f4 t={bv,bv,bv,bv}; pa[0][s]=t; }
      gemmW<2,4,4,1,1>(pa, qb + (w>>2)*16*STRP, STRP, wlds+WL_PW2, lane, 0);
      if(a4 == (w&3)){
        float* wpW = wp + w*272;
        #pragma unroll
        for(int s=0;s<4;s++)
          #pragma unroll
          for(int g=0;g<4;g++)
            wpW[g*68 + s*16 + lc] = pa[0][s][g];
      }
    }
    { // gin + loss: thread -> (d = lane&31, local rows rl0, rl0+1 of wave's 4)
      const float* wpW = wp + w*272;
      int rl0 = 2*(lane>>5), d = lane&31;
      int row0 = 4*w + rl0, row1 = row0 + 1;
      if(d==0){ obsO[row0]=o0; obsO[row1]=o1; }
      float mean0 = wpW[rl0*68 + d],     lv0 = wpW[rl0*68 + 32 + d];
      float mean1 = wpW[(rl0+1)*68 + d], lv1 = wpW[(rl0+1)*68 + 32 + d];
      float er0 = (x0-mean0)*__expf(-0.5f*lv0);
      float er1 = (x1-mean1)*__expf(-0.5f*lv1);
      lsum += 0.5f*((er0*er0 + lv0 + TWO_LOGC)*m0 + (er1*er1 + lv1 + TWO_LOGC)*m1);
      const float* wj = sbJ + d*51;
      unsigned short* g0 = un + row0*STRG;
      unsigned short* g1 = un + row1*STRG;
      #pragma unroll
      for(int pr=0;pr<PREP_;pr+=2){
        const float* ca = wj + pr*5;
        const float* cb = ca + 5;
        float sa0 = fmaxf(x0*ca[0] + mean0*ca[1] + lv0*ca[2] + er0*ca[3] + ca[4], 0.f)*m0;
        float sb0 = fmaxf(x0*cb[0] + mean0*cb[1] + lv0*cb[2] + er0*cb[3] + cb[4], 0.f)*m0;
        float sa1 = fmaxf(x1*ca[0] + mean1*ca[1] + lv1*ca[2] + er1*ca[3] + ca[4], 0.f)*m1;
        float sb1 = fmaxf(x1*cb[0] + mean1*cb[1] + lv1*cb[2] + er1*cb[3] + cb[4], 0.f)*m1;
        int pos = permk(d*PREP_ + pr);     // even, pair-adjacent (k&3 in {0,2})
        *(unsigned int*)(g0 + pos) = cvtpk(sa0, sb0);
        *(unsigned int*)(g1 + pos) = cvtpk(sa1, sb1);
      }
    }
    __syncthreads();
    // gi = gin @ [wih_r|wih_z|wih_n] (+biases); kc=0 peeled with preloaded B
    f4 gi[2][3];
    #pragma unroll
    for(int rt=0;rt<2;rt++){
      float br = sb[SB_BRZ + w*16+lc], bz = sb[SB_BRZ+128 + w*16+lc], bn = sb[SB_BIN + w*16+lc];
      f4 tr={br,br,br,br}, tz={bz,bz,bz,bz}, tn={bn,bn,bn,bn};
      gi[rt][0]=tr; gi[rt][1]=tz; gi[rt][2]=tn;
    }
    {
      const unsigned short* A = un + lc*STRG + a4*8;
      bf8 av0 = *(const bf8*)(A);
      bf8 av1 = *(const bf8*)(A + 16*STRG);
      #pragma unroll
      for(int s=0;s<3;s++){
        gi[0][s] = mfma16(av0, pre[s], gi[0][s]);
        gi[1][s] = mfma16(av1, pre[s], gi[1][s]);
      }
    }
    gemmW<9,3,24,2>(gi, un+32, STRG, blob+OFF_WIH + 24*512, lane, w);
    // epilogue: writes hb; all hb READS happened before the mid barrier.
    #pragma unroll
    for(int rt=0;rt<2;rt++)
      #pragma unroll
      for(int g=0;g<4;g++){
        int row = rt*16+a4*4+g;
        float r = sigmoidf_(gi[rt][0][g] + gh[rt][0][g]);
        float z = sigmoidf_(gi[rt][1][g] + gh[rt][1][g]);
        float nn = tanhf_(gi[rt][2][g] + r*gh[rt][2][g]);
        float hv = (1.f-z)*nn + z*hFr[rt][g];
        if(obsO[row]>=0){
          hFr[rt][g]=hv;
          hb[row*STRH + permk(w*16+lc)] = f2bf(hv);
        }
      }
    __syncthreads();
  };

  // ---- sequence ----
  qphase();                       // q for first euler
  for(int t=0;t<NT_;t++){
    // prefetch this t's jump gathers (consumed ~2 phases later).
    // mapping matches gin: thread -> (d = lane&31, rows 4w+2*(lane>>5)+{0,1})
    int rp = tid>>5, d = tid&31;
    unsigned short iv0 = inv[(size_t)t*B_ + base + rp*2];
    unsigned short iv1 = inv[(size_t)t*B_ + base + rp*2 + 1];
    int o0 = (iv0==0xFFFFu)? -1 : (int)iv0;
    int o1 = (iv1==0xFFFFu)? -1 : (int)iv1;
    float x0=0.f,m0=0.f,x1=0.f,m1=0.f;
    if(o0>=0){
      x0 = X[((size_t)t*NO_+o0)*D_ + d];
      m0 = M[((size_t)t*NO_+o0)*D_ + d];
    }
    if(o1>=0){
      x1 = X[((size_t)t*NO_+o1)*D_ + d];
      m1 = M[((size_t)t*NO_+o1)*D_ + d];
    }
    euler();
    qphase();                     // q at post-euler h (feeds jump's p + next euler)
    jump(o0, o1, x0, m0, x1, m1);
    qphase();                     // q at post-jump h (feeds next euler)
  }
  for(int it=0;it<NPOST_;it++){
    euler();
    qphase();
  }
  { // final p for output (registers only)
    f4 acc[1][1];
    { float bv = sb[SB_P2 + pct*16+lc]; f4 t={bv,bv,bv,bv}; acc[0][0]=t; }
    gemmW<2,1,4,1>(acc, qb + prt*16*STRP, STRP, wlds+WL_PW2, lane, pct);
    pFr = acc[0][0];
  }

  // ---- outputs ----
  #pragma unroll
  for(int rt=0;rt<2;rt++)
    #pragma unroll
    for(int g=0;g<4;g++)
      outH[(size_t)(base + rt*16+a4*4+g)*H_ + w*16+lc] = hFr[rt][g];
  #pragma unroll
  for(int g=0;g<4;g++)
    outP[(size_t)(base + prt*16+a4*4+g)*(2*D_) + pct*16+lc] = pFr[g];

  #pragma unroll
  for(int off=32;off>0;off>>=1) lsum += __shfl_down(lsum, off);
  if(lane==0) lred[w]=lsum;
  __syncthreads();
  if(tid==0){
    float s = 0.f;
    #pragma unroll
    for(int i=0;i<8;i++) s += lred[i];
    atomicAdd(outLoss, s);
  }
}

// ---------------- launcher ----------------
extern "C" void kernel_launch(void* const* d_in, const int* in_sizes, int n_in,
                              void* d_out, int out_size, void* d_ws, size_t ws_size,
                              hipStream_t stream){
  const float* X      = (const float*)d_in[0];
  const float* M      = (const float*)d_in[1];
  const int*   obs    = (const int*)  d_in[2];
  const float* cov    = (const float*)d_in[3];
  const float* cm_w1  = (const float*)d_in[4];
  const float* cm_b1  = (const float*)d_in[5];
  const float* cm_w2  = (const float*)d_in[6];
  const float* cm_b2  = (const float*)d_in[7];
  const float* p_w1   = (const float*)d_in[8];
  const float* p_b1   = (const float*)d_in[9];
  const float* p_w2   = (const float*)d_in[10];
  const float* p_b2   = (const float*)d_in[11];
  const float* xz_w   = (const float*)d_in[12];
  const float* xz_b   = (const float*)d_in[13];
  const float* hz_w   = (const float*)d_in[14];
  const float* xn_w   = (const float*)d_in[15];
  const float* xn_b   = (const float*)d_in[16];
  const float* hn_w   = (const float*)d_in[17];
  const float* w_ih   = (const float*)d_in[18];
  const float* w_hh   = (const float*)d_in[19];
  const float* b_ih   = (const float*)d_in[20];
  const float* b_hh   = (const float*)d_in[21];
  const float* w_prep = (const float*)d_in[22];
  const float* bprep  = (const float*)d_in[23];

  unsigned short* blob = (unsigned short*)d_ws;
  unsigned short* inv  = (unsigned short*)((char*)d_ws + INV_BYTE_OFF);
  float*          wjp  = (float*)((char*)d_ws + WJP_BYTE_OFF);
  float* outH = (float*)d_out;
  float* outP = outH + (size_t)B_*H_;
  float* outLoss = outP + (size_t)B_*2*D_;

  init_inv   <<<dim3((NT_*B_+255)/256), dim3(256), 0, stream>>>(inv, outLoss);
  scatter_inv<<<dim3((NT_*NO_+255)/256), dim3(256), 0, stream>>>(inv, obs);
  build_blobs<<<dim3(480,8), dim3(256), 0, stream>>>(p_w1,p_w2,xz_w,xn_w,hz_w,hn_w,w_ih,w_hh,
                                                     w_prep,bprep,p_b2,xz_b,xn_b, blob, wjp);
  fused      <<<dim3(B_/32), dim3(512), 0, stream>>>(
      X, M, cov, cm_w1, cm_b1, cm_w2, cm_b2, p_b1, p_b2,
      b_ih, b_hh, blob, wjp, inv, outH, outP, outLoss);
}